// Round 1
// baseline (863.270 us; speedup 1.0000x reference)
//
#include <hip/hip_runtime.h>
#include <hip/hip_bf16.h>
#include <cstdint>
#include <cstddef>

// ---------------------------------------------------------------------------
// GraphHINGE fp32 baseline.
// Sizes: B=512, L=32, N=B*L=16384, E=HID=128, HEADS=3, NMETA=5, V=100000.
// T1=T2=0.2 (multiply by 5), Z scaled by 1/HEADS.
//
// Pipeline:
//  K0  build_Bmat:  Bmat[m][e'][h*128+e] = sum_o Ws[m,h,e,o]*Wt[m,h,e',o]
//  per metapath m:
//   K1 gather_corr<P>: gather path embeddings, cross-correlate -> H[n][p'][e]
//   K2 gemm_f32:  S[n][h*128+e] = sum_e' H0[n,e'] * Bmat[m][e'][h*128+e]
//   K3 attnode<PP>: logits=H.S/T1 -> softmax -> Hbar (overwrites S in place)
//   K4 gemm_f32:  Zall[b][m][l][o] += (1/3) * Hbar[n] . Wc[m]   (zm scatter)
//  K5a gemm_f32(act=tanh): T = tanh(Zall @ pw1 + pb1)   (T aliases H buffer)
//  K5b rowdot:    w[r] = (T[r].pw2)/T2
//  K6  beta_pathout: softmax over 160 paths, path_out[b] = sum beta*z
//  K7  final_k:   sigmoid(relu([src,tgt,path_out]@fw1+fb1)@fw2+fb2)
// ---------------------------------------------------------------------------

#define NNODES 16384

// ---------------- K0: Bmat[m][e'][h*128+e] = Ws[m,h,e,:] . Wt[m,h,e',:] ----
__global__ __launch_bounds__(256) void build_Bmat(
    const float* __restrict__ Ws, const float* __restrict__ Wt,
    float* __restrict__ Bmat)
{
  int mh = blockIdx.x >> 4;   // 0..14  (m*3+h)
  int g  = blockIdx.x & 15;   // e' group of 8
  int m = mh / 3, h = mh % 3;
  const float* ws = Ws + (size_t)mh * 16384;
  const float* wt = Wt + (size_t)mh * 16384;
  int tid = threadIdx.x;
  int e = tid & 127, half = tid >> 7;
  __shared__ float wtl[2][128];
  for (int ep0 = g * 8; ep0 < g * 8 + 8; ep0 += 2) {
    int ep = ep0 + half;
    wtl[half][e] = wt[ep * 128 + e];
    __syncthreads();
    float acc = 0.f;
    #pragma unroll 4
    for (int o = 0; o < 128; ++o) acc += ws[e * 128 + o] * wtl[half][o];
    Bmat[((size_t)m * 128 + ep) * 384 + h * 128 + e] = acc;
    __syncthreads();
  }
}

// ---------------- K1: gather + cross-correlation ---------------------------
template <int P>
__global__ __launch_bounds__(256) void gather_corr(
    const float* __restrict__ Tu0, const float* __restrict__ Tu1,
    const float* __restrict__ Tu2, const float* __restrict__ Tu3,
    const float* __restrict__ Tt0, const float* __restrict__ Tt1,
    const float* __restrict__ Tt2, const float* __restrict__ Tt3,
    const int* __restrict__ idxU, const int* __restrict__ idxT,
    float* __restrict__ H)
{
  constexpr int PP = 2 * P - 1;
  int tid = threadIdx.x;
  int n = blockIdx.x * 2 + (tid >> 7);
  int e = tid & 127;
  const float* TU[4] = {Tu0, Tu1, Tu2, Tu3};
  const float* TT[4] = {Tt0, Tt1, Tt2, Tt3};
  float su[P], st[P];
  #pragma unroll
  for (int p = 0; p < P; ++p) {
    su[p] = TU[p][(size_t)idxU[n * P + p] * 128 + e];
    st[p] = TT[p][(size_t)idxT[n * P + p] * 128 + e];
  }
  float* Hn = H + (size_t)n * PP * 128 + e;
  #pragma unroll
  for (int k = 0; k < PP; ++k) {
    float acc = 0.f;
    #pragma unroll
    for (int i = 0; i < P; ++i) {
      int j = k + i - (P - 1);
      if (j >= 0 && j < P) acc += su[j] * st[i];
    }
    Hn[(size_t)k * 128] = acc;
  }
}

// ---------------- generic tiled fp32 GEMM ----------------------------------
// C[crow(n)][col] = act(alpha * sum_k A[n][k]*B[k][col] (+bias))
// zm >= 0: crow = ((n>>5)*5 + zm)*32 + (n&31)  (scatter into Zall)
// act==1: v = tanhf(v + bias[col])
__global__ __launch_bounds__(256) void gemm_f32(
    const float* __restrict__ A, int lda,
    const float* __restrict__ B, int ldb,
    float* __restrict__ C, int ldc,
    int M, int N, int K, float alpha, int zm, int act,
    const float* __restrict__ bias)
{
  __shared__ float As[16][68];
  __shared__ float Bs[16][68];
  int bn = blockIdx.x * 64;
  int bm = blockIdx.y * 64;
  int tid = threadIdx.x;
  int tm = tid >> 4, tn = tid & 15;
  float acc[4][4] = {};
  int ar  = tid >> 2;          // 0..63 (A row within tile)
  int akc = (tid & 3) << 2;    // 0,4,8,12 (k chunk)
  int bkr = tid >> 6;          // 0..3
  int bc  = tid & 63;
  for (int k0 = 0; k0 < K; k0 += 16) {
    float4 av = *(const float4*)(A + (size_t)(bm + ar) * lda + k0 + akc);
    As[akc + 0][ar] = av.x; As[akc + 1][ar] = av.y;
    As[akc + 2][ar] = av.z; As[akc + 3][ar] = av.w;
    #pragma unroll
    for (int i = 0; i < 4; ++i)
      Bs[bkr + 4 * i][bc] = B[(size_t)(k0 + bkr + 4 * i) * ldb + bn + bc];
    __syncthreads();
    #pragma unroll
    for (int kk = 0; kk < 16; ++kk) {
      float a0 = As[kk][tm * 4 + 0], a1 = As[kk][tm * 4 + 1];
      float a2 = As[kk][tm * 4 + 2], a3 = As[kk][tm * 4 + 3];
      float b0 = Bs[kk][tn * 4 + 0], b1 = Bs[kk][tn * 4 + 1];
      float b2 = Bs[kk][tn * 4 + 2], b3 = Bs[kk][tn * 4 + 3];
      acc[0][0] += a0 * b0; acc[0][1] += a0 * b1; acc[0][2] += a0 * b2; acc[0][3] += a0 * b3;
      acc[1][0] += a1 * b0; acc[1][1] += a1 * b1; acc[1][2] += a1 * b2; acc[1][3] += a1 * b3;
      acc[2][0] += a2 * b0; acc[2][1] += a2 * b1; acc[2][2] += a2 * b2; acc[2][3] += a2 * b3;
      acc[3][0] += a3 * b0; acc[3][1] += a3 * b1; acc[3][2] += a3 * b2; acc[3][3] += a3 * b3;
    }
    __syncthreads();
  }
  #pragma unroll
  for (int i = 0; i < 4; ++i) {
    int n0 = bm + tm * 4 + i;
    int crow = n0;
    if (zm >= 0) crow = (((n0 >> 5) * 5 + zm) << 5) + (n0 & 31);
    #pragma unroll
    for (int j = 0; j < 4; ++j) {
      int col = bn + tn * 4 + j;
      float v = acc[i][j] * alpha;
      if (act == 1) v = tanhf(v + bias[col]);
      C[(size_t)crow * ldc + col] = v;
    }
  }
}

// ---------------- K3: node attention (softmax over p'), Hbar in place -----
template <int PP>
__global__ __launch_bounds__(384) void attnode(
    const float* __restrict__ H, float* __restrict__ S)
{
  int n = blockIdx.x;
  int tid = threadIdx.x;
  int h = tid >> 7, e = tid & 127;
  __shared__ float hs[PP * 128];
  __shared__ float partial[6][PP];
  __shared__ float al[3][PP];
  const float* Hn = H + (size_t)n * PP * 128;
  for (int idx = tid; idx < PP * 128; idx += 384) hs[idx] = Hn[idx];
  float s_he = S[(size_t)n * 384 + tid];
  __syncthreads();
  int lane = tid & 63, wid = tid >> 6;
  #pragma unroll
  for (int p = 0; p < PP; ++p) {
    float v = hs[p * 128 + e] * s_he;
    #pragma unroll
    for (int off = 32; off; off >>= 1) v += __shfl_down(v, off);
    if (lane == 0) partial[wid][p] = v;
  }
  __syncthreads();
  if ((tid & 127) == 0) {
    float lg[PP];
    float mx = -1e30f;
    #pragma unroll
    for (int p = 0; p < PP; ++p) {
      lg[p] = (partial[2 * h][p] + partial[2 * h + 1][p]) * 5.0f;  // /T1
      mx = fmaxf(mx, lg[p]);
    }
    float sum = 0.f;
    #pragma unroll
    for (int p = 0; p < PP; ++p) { lg[p] = expf(lg[p] - mx); sum += lg[p]; }
    float inv = 1.0f / sum;
    #pragma unroll
    for (int p = 0; p < PP; ++p) al[h][p] = lg[p] * inv;
  }
  __syncthreads();
  float acc = 0.f;
  #pragma unroll
  for (int p = 0; p < PP; ++p) acc += al[h][p] * hs[p * 128 + e];
  S[(size_t)n * 384 + tid] = acc;
}

// ---------------- K5b: w[r] = (T[r,:].pw2)/T2 ------------------------------
__global__ __launch_bounds__(256) void rowdot(
    const float* __restrict__ T, const float* __restrict__ pw2,
    float* __restrict__ w)
{
  int tid = threadIdx.x;
  int r = blockIdx.x * 2 + (tid >> 7);
  int e = tid & 127;
  float v = T[(size_t)r * 128 + e] * pw2[e];
  #pragma unroll
  for (int off = 32; off; off >>= 1) v += __shfl_down(v, off);
  __shared__ float red[4];
  int wid = tid >> 6;
  if ((tid & 63) == 0) red[wid] = v;
  __syncthreads();
  if ((tid & 127) == 0) w[r] = (red[wid] + red[wid + 1]) * 5.0f;  // /T2
}

// ---------------- K6: beta softmax over 160 paths + weighted sum -----------
__global__ __launch_bounds__(128) void beta_pathout(
    const float* __restrict__ w, const float* __restrict__ Zall,
    float* __restrict__ pout)
{
  int b = blockIdx.x, tid = threadIdx.x;
  __shared__ float bw[160];
  __shared__ float mx_s, denom_s;
  bw[tid] = w[b * 160 + tid];
  if (tid < 32) bw[128 + tid] = w[b * 160 + 128 + tid];
  __syncthreads();
  if (tid == 0) {
    float mx = -1e30f;
    for (int j = 0; j < 160; ++j) mx = fmaxf(mx, bw[j]);
    float s = 0.f;
    for (int j = 0; j < 160; ++j) s += expf(bw[j] - mx);
    mx_s = mx; denom_s = s;
  }
  __syncthreads();
  float mx = mx_s, inv = 1.0f / denom_s;
  for (int j = tid; j < 160; j += 128) bw[j] = expf(bw[j] - mx) * inv;
  __syncthreads();
  float acc = 0.f;
  for (int j = 0; j < 160; ++j)
    acc += bw[j] * Zall[((size_t)b * 160 + j) * 128 + tid];
  pout[b * 128 + tid] = acc;
}

// ---------------- K7: final MLP + sigmoid ----------------------------------
__global__ __launch_bounds__(128) void final_k(
    const int* __restrict__ UI, const int* __restrict__ IU,
    const float* __restrict__ emb_user, const float* __restrict__ emb_item,
    const float* __restrict__ pout,
    const float* __restrict__ fw1, const float* __restrict__ fb1,
    const float* __restrict__ fw2, const float* __restrict__ fb2,
    float* __restrict__ out)
{
  int b = blockIdx.x, tid = threadIdx.x;
  __shared__ float x[384];
  int su = UI[b * 64];  // UI[b][0][0]
  int ti = IU[b * 64];  // IU[b][0][0]
  x[tid]       = emb_user[(size_t)su * 128 + tid];
  x[128 + tid] = emb_item[(size_t)ti * 128 + tid];
  x[256 + tid] = pout[b * 128 + tid];
  __syncthreads();
  float acc = fb1[tid];
  #pragma unroll 4
  for (int i = 0; i < 384; ++i) acc += x[i] * fw1[i * 128 + tid];
  float y = fmaxf(acc, 0.0f) * fw2[tid];
  #pragma unroll
  for (int off = 32; off; off >>= 1) y += __shfl_down(y, off);
  __shared__ float red[2];
  if ((tid & 63) == 0) red[tid >> 6] = y;
  __syncthreads();
  if (tid == 0) {
    float s = red[0] + red[1] + fb2[0];
    out[b] = 1.0f / (1.0f + expf(-s));
  }
}

// ---------------------------------------------------------------------------
extern "C" void kernel_launch(void* const* d_in, const int* in_sizes, int n_in,
                              void* d_out, int out_size, void* d_ws, size_t ws_size,
                              hipStream_t stream)
{
  const int* UI    = (const int*)d_in[0];
  const int* IU    = (const int*)d_in[1];
  const int* UIUI  = (const int*)d_in[2];
  const int* IUIU  = (const int*)d_in[3];
  const int* UIAI1 = (const int*)d_in[4];
  const int* IAIU1 = (const int*)d_in[5];
  const int* UIAI2 = (const int*)d_in[6];
  const int* IAIU2 = (const int*)d_in[7];
  const int* UIAI3 = (const int*)d_in[8];
  const int* IAIU3 = (const int*)d_in[9];
  const float* emb_user = (const float*)d_in[10];
  const float* emb_item = (const float*)d_in[11];
  const float* emb_a1   = (const float*)d_in[12];
  const float* emb_a2   = (const float*)d_in[13];
  const float* emb_a3   = (const float*)d_in[14];
  const float* Wt  = (const float*)d_in[15];
  const float* Ws  = (const float*)d_in[16];
  const float* Wc  = (const float*)d_in[17];
  const float* pw1 = (const float*)d_in[18];
  const float* pb1 = (const float*)d_in[19];
  const float* pw2 = (const float*)d_in[20];
  const float* fw1 = (const float*)d_in[21];
  const float* fb1 = (const float*)d_in[22];
  const float* fw2 = (const float*)d_in[23];
  const float* fb2 = (const float*)d_in[24];
  float* out = (float*)d_out;

  float* ws = (float*)d_ws;
  // workspace layout (floats):
  float* Bmat = ws;                       // 5*128*384      = 245760
  float* H    = ws + 245760;              // 16384*7*128    = 14680064
  float* S    = ws + 14925824;            // 16384*384      = 6291456
  float* Zall = ws + 21217280;            // 16384*5*128    = 10485760
  float* wbuf = ws + 31703040;            // 512*160        = 81920
  float* pout = ws + 31784960;            // 512*128        = 65536
  float* Tbuf = H;                        // alias: 81920*128 <= 14680064

  build_Bmat<<<240, 256, 0, stream>>>(Ws, Wt, Bmat);

  const int*   idxU[5] = {UI, UIUI, UIAI1, UIAI2, UIAI3};
  const int*   idxT[5] = {IU, IUIU, IAIU1, IAIU2, IAIU3};
  const float* u2[5] = {nullptr, emb_user, emb_a1, emb_a2, emb_a3};
  const float* t1[5] = {emb_user, emb_user, emb_a1, emb_a2, emb_a3};

  for (int m = 0; m < 5; ++m) {
    if (m == 0) {
      gather_corr<2><<<8192, 256, 0, stream>>>(
          emb_user, emb_item, nullptr, nullptr,
          emb_item, emb_user, nullptr, nullptr,
          idxU[m], idxT[m], H);
    } else {
      // user path: [user, item, X, item]; item path: [item, X, item, user]
      gather_corr<4><<<8192, 256, 0, stream>>>(
          emb_user, emb_item, u2[m], emb_item,
          emb_item, t1[m], emb_item, emb_user,
          idxU[m], idxT[m], H);
    }
    int PP = (m == 0) ? 3 : 7;
    // S = H0 @ Bmat[m]   (16384 x 384, K=128)
    gemm_f32<<<dim3(6, 256), 256, 0, stream>>>(
        H, PP * 128, Bmat + (size_t)m * 49152, 384, S, 384,
        NNODES, 384, 128, 1.0f, -1, 0, nullptr);
    if (m == 0) attnode<3><<<NNODES, 384, 0, stream>>>(H, S);
    else        attnode<7><<<NNODES, 384, 0, stream>>>(H, S);
    // Zall[m-slice] = (1/3) * Hbar @ Wc[m]   (16384 x 128, K=384)
    gemm_f32<<<dim3(2, 256), 256, 0, stream>>>(
        S, 384, Wc + (size_t)m * 49152, 128, Zall, 128,
        NNODES, 128, 384, (1.0f / 3.0f), m, 0, nullptr);
  }

  // T = tanh(Zall @ pw1 + pb1)   (81920 x 128, K=128)
  gemm_f32<<<dim3(2, 1280), 256, 0, stream>>>(
      Zall, 128, pw1, 128, Tbuf, 128,
      81920, 128, 128, 1.0f, -1, 1, pb1);
  rowdot<<<40960, 256, 0, stream>>>(Tbuf, pw2, wbuf);
  beta_pathout<<<512, 128, 0, stream>>>(wbuf, Zall, pout);
  final_k<<<512, 128, 0, stream>>>(UI, IU, emb_user, emb_item, pout,
                                   fw1, fb1, fw2, fb2, out);
}

// Round 2
// 339.586 us; speedup vs baseline: 2.5421x; 2.5421x over previous
//
#include <hip/hip_runtime.h>
#include <hip/hip_bf16.h>
#include <cstdint>
#include <cstddef>

// ---------------------------------------------------------------------------
// GraphHINGE, round 1: MFMA-fused middle.
//  prep:  build_BmatT (bf16 [m][384][128]), conv_WcT (bf16 [m][128][384]),
//         conv_pw1T (bf16 [128][128])
//  per metapath m:
//   gather_corr<P>: gather + cross-correlate -> H bf16, padded layout
//                   [n][p*136+e], node stride NS (968 for PP=7, 408 for PP=3)
//   fused_mid<PP>:  per 16-node block: stage H in LDS ->
//                   S=H0@BmatT (MFMA) -> logits -> softmax -> Hbar ->
//                   Z=Hbar@WcT (MFMA) -> scatter to Zall (f32)
//  fused_path: T=tanh(Zall@pw1+pb1) (MFMA) fused with rowdot -> w
//  beta_pathout, final_k: unchanged from validated round 0.
// ---------------------------------------------------------------------------

typedef __hip_bfloat16 bf16;
typedef __attribute__((ext_vector_type(8))) short  bfrag;   // 8 bf16 (4 VGPR)
typedef __attribute__((ext_vector_type(4))) float  ffrag;   // 4 f32 acc

#define NNODES 16384

__device__ __forceinline__ float bflo(uint32_t u) { return __uint_as_float(u << 16); }
__device__ __forceinline__ float bfhi(uint32_t u) { return __uint_as_float(u & 0xffff0000u); }

// ---------------- prep: BmatT[m][h*128+e][ep] = Ws[m,h,e,:].Wt[m,h,ep,:] ---
__global__ __launch_bounds__(256) void build_BmatT(
    const float* __restrict__ Ws, const float* __restrict__ Wt,
    bf16* __restrict__ BmT)
{
  int mh = blockIdx.x >> 4;   // m*3+h
  int g  = blockIdx.x & 15;
  int m = mh / 3, h = mh % 3;
  const float* ws = Ws + (size_t)mh * 16384;
  const float* wt = Wt + (size_t)mh * 16384;
  int tid = threadIdx.x;
  int e = tid & 127, half = tid >> 7;
  __shared__ float wtl[2][128];
  for (int ep0 = g * 8; ep0 < g * 8 + 8; ep0 += 2) {
    int ep = ep0 + half;
    wtl[half][e] = wt[ep * 128 + e];
    __syncthreads();
    float acc = 0.f;
    #pragma unroll 4
    for (int o = 0; o < 128; ++o) acc += ws[e * 128 + o] * wtl[half][o];
    BmT[((size_t)(m * 384 + h * 128 + e)) * 128 + ep] = __float2bfloat16(acc);
    __syncthreads();
  }
}

// ---------------- prep: WcT[m][o][he] = Wc[m][he][o] -----------------------
__global__ __launch_bounds__(256) void conv_WcT(
    const float* __restrict__ Wc, bf16* __restrict__ WcT)
{
  int idx = blockIdx.x * 256 + threadIdx.x;   // < 5*128*384
  int he = idx % 384, mo = idx / 384;
  int m = mo >> 7, o = mo & 127;
  WcT[idx] = __float2bfloat16(Wc[((size_t)m * 384 + he) * 128 + o]);
}

// ---------------- prep: pw1T[o][k] = pw1[k][o] -----------------------------
__global__ __launch_bounds__(256) void conv_pw1T(
    const float* __restrict__ pw1, bf16* __restrict__ pw1T)
{
  int idx = blockIdx.x * 256 + threadIdx.x;   // < 16384
  int o = idx >> 7, k = idx & 127;
  pw1T[idx] = __float2bfloat16(pw1[(size_t)k * 128 + o]);
}

// ---------------- gather + cross-correlation, bf16 padded output ----------
template <int P>
__global__ __launch_bounds__(256) void gather_corr(
    const float* __restrict__ Tu0, const float* __restrict__ Tu1,
    const float* __restrict__ Tu2, const float* __restrict__ Tu3,
    const float* __restrict__ Tt0, const float* __restrict__ Tt1,
    const float* __restrict__ Tt2, const float* __restrict__ Tt3,
    const int* __restrict__ idxU, const int* __restrict__ idxT,
    bf16* __restrict__ H)
{
  constexpr int PP = 2 * P - 1;
  constexpr int NS = (P == 4) ? 968 : 408;   // padded node stride
  int tid = threadIdx.x;
  int n = blockIdx.x * 2 + (tid >> 7);
  int e = tid & 127;
  const float* TU[4] = {Tu0, Tu1, Tu2, Tu3};
  const float* TT[4] = {Tt0, Tt1, Tt2, Tt3};
  float su[P], st[P];
  #pragma unroll
  for (int p = 0; p < P; ++p) {
    su[p] = TU[p][(size_t)idxU[n * P + p] * 128 + e];
    st[p] = TT[p][(size_t)idxT[n * P + p] * 128 + e];
  }
  bf16* Hn = H + (size_t)n * NS;
  #pragma unroll
  for (int k = 0; k < PP; ++k) {
    float acc = 0.f;
    #pragma unroll
    for (int i = 0; i < P; ++i) {
      int j = k + i - (P - 1);
      if (j >= 0 && j < P) acc += su[j] * st[i];
    }
    Hn[k * 136 + e] = __float2bfloat16(acc);
  }
  // zero the pads (never consumed, but keep LDS contents defined)
  if (e < 8) {
    #pragma unroll
    for (int k = 0; k < PP; ++k) Hn[k * 136 + 128 + e] = __float2bfloat16(0.f);
  }
  if (P == 4 && e < 16) Hn[952 + e] = __float2bfloat16(0.f);
}

// ---------------- fused per-metapath middle --------------------------------
// block = 16 nodes, 256 threads (4 waves); grid = 1024
template <int PP>
__global__ __launch_bounds__(256) void fused_mid(
    const bf16* __restrict__ Hg,     // [16384][NS]
    const bf16* __restrict__ BmT,    // [384][128] (this metapath)
    const bf16* __restrict__ WcT,    // [128][384]
    float* __restrict__ Zall, int m)
{
  constexpr int NS = (PP == 7) ? 968 : 408;
  constexpr int NPAIR = 3 * PP;
  __shared__ bf16 Hs[16 * NS];
  __shared__ bf16 Ss[16 * 392];          // S, later aliased as Hbar
  __shared__ float lg[16][3][8];
  __shared__ float alpha[16][3][8];

  int tid = threadIdx.x;
  int lane = tid & 63, wid = tid >> 6;
  int l15 = lane & 15, l4 = lane >> 4;
  int n0 = blockIdx.x * 16;

  // ---- stage H tile (contiguous span, 16B vector copies) ----
  {
    const float4* src = (const float4*)(Hg + (size_t)n0 * NS);
    float4* dst = (float4*)Hs;
    constexpr int NVEC = (16 * NS * 2) / 16;   // 1936 (PP=7) / 816 (PP=3)
    for (int i = tid; i < NVEC; i += 256) dst[i] = src[i];
  }
  __syncthreads();

  // ---- S = H0 @ BmatT : M=16, N=384, K=128 (wave: 6 col-frags) ----
  {
    bfrag a[4];
    #pragma unroll
    for (int kk = 0; kk < 4; ++kk)
      a[kk] = *(const bfrag*)&Hs[l15 * NS + kk * 32 + 8 * l4];
    #pragma unroll
    for (int f = 0; f < 6; ++f) {
      int col = wid * 96 + f * 16 + l15;
      ffrag acc = {0.f, 0.f, 0.f, 0.f};
      #pragma unroll
      for (int kk = 0; kk < 4; ++kk) {
        bfrag b = *(const bfrag*)&BmT[(size_t)col * 128 + kk * 32 + 8 * l4];
        acc = __builtin_amdgcn_mfma_f32_16x16x32_bf16(a[kk], b, acc, 0, 0, 0);
      }
      #pragma unroll
      for (int r = 0; r < 4; ++r) {
        int node = 4 * l4 + r;
        Ss[node * 392 + col] = __float2bfloat16(acc[r]);
      }
    }
  }
  __syncthreads();

  // ---- logits[node][h][p] = (H[p,:].S[h,:]) * 5  (1/T1) ----
  {
    int node = tid >> 4, q = tid & 15;
    for (int pp = q; pp < NPAIR; pp += 16) {
      int h = pp / PP, p = pp - h * PP;
      const uint32_t* hrow = (const uint32_t*)&Hs[node * NS + p * 136];
      const uint32_t* srow = (const uint32_t*)&Ss[node * 392 + h * 128];
      float acc = 0.f;
      #pragma unroll 8
      for (int i = 0; i < 64; ++i) {
        uint32_t hv = hrow[i], sv = srow[i];
        acc += bflo(hv) * bflo(sv) + bfhi(hv) * bfhi(sv);
      }
      lg[node][h][p] = acc * 5.0f;
    }
  }
  __syncthreads();

  // ---- softmax over p, per (node, head) ----
  if (tid < 48) {
    int nd = tid / 3, h = tid - nd * 3;
    float mx = -1e30f;
    #pragma unroll
    for (int p = 0; p < PP; ++p) mx = fmaxf(mx, lg[nd][h][p]);
    float s = 0.f, ev[8];
    #pragma unroll
    for (int p = 0; p < PP; ++p) { ev[p] = expf(lg[nd][h][p] - mx); s += ev[p]; }
    float inv = 1.0f / s;
    #pragma unroll
    for (int p = 0; p < PP; ++p) alpha[nd][h][p] = ev[p] * inv;
  }
  __syncthreads();

  // ---- Hbar[node][h*128+e] = sum_p alpha*H  -> overwrite Ss (bf16) ----
  {
    int node = tid >> 4, q = tid & 15;
    #pragma unroll
    for (int c = 0; c < 12; ++c) {
      int o2 = q * 12 + c;            // 192 bf16-pairs per node
      int h = o2 >> 6, e = (o2 & 63) * 2;
      float a0 = 0.f, a1 = 0.f;
      #pragma unroll
      for (int p = 0; p < PP; ++p) {
        float al = alpha[node][h][p];
        uint32_t hv = *(const uint32_t*)&Hs[node * NS + p * 136 + e];
        a0 += al * bflo(hv);
        a1 += al * bfhi(hv);
      }
      Ss[node * 392 + h * 128 + e]     = __float2bfloat16(a0);
      Ss[node * 392 + h * 128 + e + 1] = __float2bfloat16(a1);
    }
  }
  __syncthreads();

  // ---- Z = Hbar @ WcT / 3 : M=16, N=128, K=384 (wave: 2 col-frags) ----
  {
    bfrag a[12];
    #pragma unroll
    for (int kk = 0; kk < 12; ++kk)
      a[kk] = *(const bfrag*)&Ss[l15 * 392 + kk * 32 + 8 * l4];
    #pragma unroll
    for (int f = 0; f < 2; ++f) {
      int col = wid * 32 + f * 16 + l15;
      ffrag acc = {0.f, 0.f, 0.f, 0.f};
      #pragma unroll
      for (int kk = 0; kk < 12; ++kk) {
        bfrag b = *(const bfrag*)&WcT[(size_t)col * 384 + kk * 32 + 8 * l4];
        acc = __builtin_amdgcn_mfma_f32_16x16x32_bf16(a[kk], b, acc, 0, 0, 0);
      }
      #pragma unroll
      for (int r = 0; r < 4; ++r) {
        int gn = n0 + 4 * l4 + r;
        int crow = (((gn >> 5) * 5 + m) << 5) + (gn & 31);
        Zall[(size_t)crow * 128 + col] = acc[r] * (1.0f / 3.0f);
      }
    }
  }
}

// ---------------- fused tanh-GEMM + rowdot ---------------------------------
// T = tanh(Zall@pw1 + pb1); w[row] = (T[row,:].pw2)*5.  M=81920,N=128,K=128.
__global__ __launch_bounds__(256) void fused_path(
    const float* __restrict__ Zall, const bf16* __restrict__ pw1T,
    const float* __restrict__ pb1, const float* __restrict__ pw2,
    float* __restrict__ w)
{
  __shared__ bf16 As[64 * 136];
  int tid = threadIdx.x;
  int lane = tid & 63, wid = tid >> 6;
  int l15 = lane & 15, l4 = lane >> 4;
  int r0 = blockIdx.x * 64;

  // stage 64 rows of Zall (f32) -> bf16 LDS
  {
    const float4* src = (const float4*)(Zall + (size_t)r0 * 128);
    for (int i = 0; i < 8; ++i) {
      int v = i * 256 + tid;            // 0..2047 float4 chunks
      int row = v >> 5, c4 = v & 31;
      float4 x = src[v];
      bf16* d = &As[row * 136 + c4 * 4];
      d[0] = __float2bfloat16(x.x); d[1] = __float2bfloat16(x.y);
      d[2] = __float2bfloat16(x.z); d[3] = __float2bfloat16(x.w);
    }
  }
  __syncthreads();

  // wave wid: rows wid*16..+15 (1 row-frag), all 128 cols (8 col-frags)
  bfrag a[4];
  #pragma unroll
  for (int kk = 0; kk < 4; ++kk)
    a[kk] = *(const bfrag*)&As[(wid * 16 + l15) * 136 + kk * 32 + 8 * l4];
  float part[4] = {0.f, 0.f, 0.f, 0.f};
  #pragma unroll
  for (int f = 0; f < 8; ++f) {
    int col = f * 16 + l15;
    ffrag acc = {0.f, 0.f, 0.f, 0.f};
    #pragma unroll
    for (int kk = 0; kk < 4; ++kk) {
      bfrag b = *(const bfrag*)&pw1T[(size_t)col * 128 + kk * 32 + 8 * l4];
      acc = __builtin_amdgcn_mfma_f32_16x16x32_bf16(a[kk], b, acc, 0, 0, 0);
    }
    float bias = pb1[col], w2 = pw2[col];
    #pragma unroll
    for (int r = 0; r < 4; ++r) part[r] += tanhf(acc[r] + bias) * w2;
  }
  // reduce across 16 lanes (col space)
  #pragma unroll
  for (int d = 1; d < 16; d <<= 1) {
    #pragma unroll
    for (int r = 0; r < 4; ++r) part[r] += __shfl_xor(part[r], d);
  }
  if (l15 == 0) {
    #pragma unroll
    for (int r = 0; r < 4; ++r)
      w[r0 + wid * 16 + 4 * l4 + r] = part[r] * 5.0f;   // /T2
  }
}

// ---------------- beta softmax over 160 paths + weighted sum ---------------
__global__ __launch_bounds__(128) void beta_pathout(
    const float* __restrict__ w, const float* __restrict__ Zall,
    float* __restrict__ pout)
{
  int b = blockIdx.x, tid = threadIdx.x;
  __shared__ float bw[160];
  __shared__ float mx_s, denom_s;
  bw[tid] = w[b * 160 + tid];
  if (tid < 32) bw[128 + tid] = w[b * 160 + 128 + tid];
  __syncthreads();
  if (tid == 0) {
    float mx = -1e30f;
    for (int j = 0; j < 160; ++j) mx = fmaxf(mx, bw[j]);
    float s = 0.f;
    for (int j = 0; j < 160; ++j) s += expf(bw[j] - mx);
    mx_s = mx; denom_s = s;
  }
  __syncthreads();
  float mx = mx_s, inv = 1.0f / denom_s;
  for (int j = tid; j < 160; j += 128) bw[j] = expf(bw[j] - mx) * inv;
  __syncthreads();
  float acc = 0.f;
  for (int j = 0; j < 160; ++j)
    acc += bw[j] * Zall[((size_t)b * 160 + j) * 128 + tid];
  pout[b * 128 + tid] = acc;
}

// ---------------- final MLP + sigmoid --------------------------------------
__global__ __launch_bounds__(128) void final_k(
    const int* __restrict__ UI, const int* __restrict__ IU,
    const float* __restrict__ emb_user, const float* __restrict__ emb_item,
    const float* __restrict__ pout,
    const float* __restrict__ fw1, const float* __restrict__ fb1,
    const float* __restrict__ fw2, const float* __restrict__ fb2,
    float* __restrict__ out)
{
  int b = blockIdx.x, tid = threadIdx.x;
  __shared__ float x[384];
  int su = UI[b * 64];
  int ti = IU[b * 64];
  x[tid]       = emb_user[(size_t)su * 128 + tid];
  x[128 + tid] = emb_item[(size_t)ti * 128 + tid];
  x[256 + tid] = pout[b * 128 + tid];
  __syncthreads();
  float acc = fb1[tid];
  #pragma unroll 4
  for (int i = 0; i < 384; ++i) acc += x[i] * fw1[i * 128 + tid];
  float y = fmaxf(acc, 0.0f) * fw2[tid];
  #pragma unroll
  for (int off = 32; off; off >>= 1) y += __shfl_down(y, off);
  __shared__ float red[2];
  if ((tid & 63) == 0) red[tid >> 6] = y;
  __syncthreads();
  if (tid == 0) {
    float s = red[0] + red[1] + fb2[0];
    out[b] = 1.0f / (1.0f + expf(-s));
  }
}

// ---------------------------------------------------------------------------
extern "C" void kernel_launch(void* const* d_in, const int* in_sizes, int n_in,
                              void* d_out, int out_size, void* d_ws, size_t ws_size,
                              hipStream_t stream)
{
  const int* UI    = (const int*)d_in[0];
  const int* IU    = (const int*)d_in[1];
  const int* UIUI  = (const int*)d_in[2];
  const int* IUIU  = (const int*)d_in[3];
  const int* UIAI1 = (const int*)d_in[4];
  const int* IAIU1 = (const int*)d_in[5];
  const int* UIAI2 = (const int*)d_in[6];
  const int* IAIU2 = (const int*)d_in[7];
  const int* UIAI3 = (const int*)d_in[8];
  const int* IAIU3 = (const int*)d_in[9];
  const float* emb_user = (const float*)d_in[10];
  const float* emb_item = (const float*)d_in[11];
  const float* emb_a1   = (const float*)d_in[12];
  const float* emb_a2   = (const float*)d_in[13];
  const float* emb_a3   = (const float*)d_in[14];
  const float* Wt  = (const float*)d_in[15];
  const float* Ws  = (const float*)d_in[16];
  const float* Wc  = (const float*)d_in[17];
  const float* pw1 = (const float*)d_in[18];
  const float* pb1 = (const float*)d_in[19];
  const float* pw2 = (const float*)d_in[20];
  const float* fw1 = (const float*)d_in[21];
  const float* fb1 = (const float*)d_in[22];
  const float* fw2 = (const float*)d_in[23];
  const float* fb2 = (const float*)d_in[24];
  float* out = (float*)d_out;

  // ---- workspace carve (bytes, 256-aligned) ----
  char* wsb = (char*)d_ws;
  bf16*  BmT  = (bf16*)wsb;                                   // 491,520 B
  bf16*  WcT  = (bf16*)(wsb + 491520);                        // 491,520 B
  bf16*  pw1T = (bf16*)(wsb + 983040);                        //  32,768 B
  bf16*  H    = (bf16*)(wsb + 1015808);                       // 31,719,424 B
  float* Zall = (float*)(wsb + 1015808 + 31719424);           // 33,554,432 B
  float* wbuf = (float*)(wsb + 1015808 + 31719424 + 33554432);//    327,680 B
  float* pout = (float*)(wsb + 1015808 + 31719424 + 33554432 + 327680);

  build_BmatT<<<240, 256, 0, stream>>>(Ws, Wt, BmT);
  conv_WcT<<<960, 256, 0, stream>>>(Wc, WcT);
  conv_pw1T<<<64, 256, 0, stream>>>(pw1, pw1T);

  const int* idxU[5] = {UI, UIUI, UIAI1, UIAI2, UIAI3};
  const int* idxT[5] = {IU, IUIU, IAIU1, IAIU2, IAIU3};
  const float* u2[5] = {nullptr, emb_user, emb_a1, emb_a2, emb_a3};
  const float* t1[5] = {emb_user, emb_user, emb_a1, emb_a2, emb_a3};

  for (int m = 0; m < 5; ++m) {
    if (m == 0) {
      gather_corr<2><<<8192, 256, 0, stream>>>(
          emb_user, emb_item, nullptr, nullptr,
          emb_item, emb_user, nullptr, nullptr,
          idxU[m], idxT[m], H);
      fused_mid<3><<<1024, 256, 0, stream>>>(
          H, BmT, WcT, Zall, m);
    } else {
      gather_corr<4><<<8192, 256, 0, stream>>>(
          emb_user, emb_item, u2[m], emb_item,
          emb_item, t1[m], emb_item, emb_user,
          idxU[m], idxT[m], H);
      fused_mid<7><<<1024, 256, 0, stream>>>(
          H, BmT + (size_t)m * 384 * 128, WcT + (size_t)m * 128 * 384, Zall, m);
    }
  }

  fused_path<<<1280, 256, 0, stream>>>(Zall, pw1T, pb1, pw2, wbuf);
  beta_pathout<<<512, 128, 0, stream>>>(wbuf, Zall, pout);
  final_k<<<512, 128, 0, stream>>>(UI, IU, emb_user, emb_item, pout,
                                   fw1, fb1, fw2, fb2, out);
}

// Round 3
// 245.487 us; speedup vs baseline: 3.5166x; 1.3833x over previous
//
#include <hip/hip_runtime.h>
#include <hip/hip_bf16.h>
#include <cstdint>
#include <cstddef>

// ---------------------------------------------------------------------------
// GraphHINGE, round 2: fully fused.
//  prep:  build_BmatT (bf16 [m][384][128]), conv_WcT (bf16 [m][128][384]),
//         conv_pw1T (bf16 [128][128])
//  per metapath m:
//   fused_metapath<P>: per 16-node block (512 thr): gather embeddings ->
//     cross-correlate into LDS Hs -> S=H0@BmatT (MFMA) -> logits ->
//     softmax -> Hbar -> Z=Hbar@WcT (MFMA) -> scatter into Zall (f32).
//  fused_tail: per-b block (256 thr): stage z[160][128] -> tanh-MFMA ->
//     w -> softmax(beta) -> pout -> final MLP -> sigmoid -> out[b].
// ---------------------------------------------------------------------------

typedef __hip_bfloat16 bf16;
typedef __attribute__((ext_vector_type(8))) short  bfrag;   // 8 bf16 (4 VGPR)
typedef __attribute__((ext_vector_type(4))) float  ffrag;   // 4 f32 acc

#define NNODES 16384

__device__ __forceinline__ float bflo(uint32_t u) { return __uint_as_float(u << 16); }
__device__ __forceinline__ float bfhi(uint32_t u) { return __uint_as_float(u & 0xffff0000u); }

// ---------------- prep: BmatT[m][h*128+e][ep] = Ws[m,h,e,:].Wt[m,h,ep,:] ---
__global__ __launch_bounds__(256) void build_BmatT(
    const float* __restrict__ Ws, const float* __restrict__ Wt,
    bf16* __restrict__ BmT)
{
  int mh = blockIdx.x >> 4;   // m*3+h
  int g  = blockIdx.x & 15;
  int m = mh / 3, h = mh % 3;
  const float* ws = Ws + (size_t)mh * 16384;
  const float* wt = Wt + (size_t)mh * 16384;
  int tid = threadIdx.x;
  int e = tid & 127, half = tid >> 7;
  __shared__ float wtl[2][128];
  for (int ep0 = g * 8; ep0 < g * 8 + 8; ep0 += 2) {
    int ep = ep0 + half;
    wtl[half][e] = wt[ep * 128 + e];
    __syncthreads();
    float acc = 0.f;
    #pragma unroll 4
    for (int o = 0; o < 128; ++o) acc += ws[e * 128 + o] * wtl[half][o];
    BmT[((size_t)(m * 384 + h * 128 + e)) * 128 + ep] = __float2bfloat16(acc);
    __syncthreads();
  }
}

// ---------------- prep: WcT[m][o][he] = Wc[m][he][o] -----------------------
__global__ __launch_bounds__(256) void conv_WcT(
    const float* __restrict__ Wc, bf16* __restrict__ WcT)
{
  int idx = blockIdx.x * 256 + threadIdx.x;   // < 5*128*384
  int he = idx % 384, mo = idx / 384;
  int m = mo >> 7, o = mo & 127;
  WcT[idx] = __float2bfloat16(Wc[((size_t)m * 384 + he) * 128 + o]);
}

// ---------------- prep: pw1T[o][k] = pw1[k][o] -----------------------------
__global__ __launch_bounds__(256) void conv_pw1T(
    const float* __restrict__ pw1, bf16* __restrict__ pw1T)
{
  int idx = blockIdx.x * 256 + threadIdx.x;   // < 16384
  int o = idx >> 7, k = idx & 127;
  pw1T[idx] = __float2bfloat16(pw1[(size_t)k * 128 + o]);
}

// ---------------- fused per-metapath: gather+corr+attention+Z --------------
// block = 16 nodes, 512 threads (8 waves); grid = 1024
template <int P>
__global__ __launch_bounds__(512) void fused_metapath(
    const float* __restrict__ Tu0, const float* __restrict__ Tu1,
    const float* __restrict__ Tu2, const float* __restrict__ Tu3,
    const float* __restrict__ Tt0, const float* __restrict__ Tt1,
    const float* __restrict__ Tt2, const float* __restrict__ Tt3,
    const int* __restrict__ idxU, const int* __restrict__ idxT,
    const bf16* __restrict__ BmT,    // [384][128] (this metapath)
    const bf16* __restrict__ WcT,    // [128][384]
    float* __restrict__ Zall, int m)
{
  constexpr int PP = 2 * P - 1;
  constexpr int NS = PP * 136;       // node stride in Hs (bf16), 16B-aligned
  constexpr int NPAIR = 3 * PP;
  __shared__ bf16 Hs[16 * NS];
  __shared__ bf16 Ss[16 * 392];      // S, later aliased as Hbar
  __shared__ float lg[16][3][8];
  __shared__ float alpha[16][3][8];

  int tid = threadIdx.x;
  int lane = tid & 63, wid = tid >> 6;
  int l15 = lane & 15, l4 = lane >> 4;
  int n0 = blockIdx.x * 16;

  // ---- gather + cross-correlate -> Hs (bf16) ----
  {
    const float* TU[4] = {Tu0, Tu1, Tu2, Tu3};
    const float* TT[4] = {Tt0, Tt1, Tt2, Tt3};
    int e = tid & 127;
    #pragma unroll
    for (int g = 0; g < 4; ++g) {
      int ln = g * 4 + (tid >> 7);           // local node 0..15
      int n = n0 + ln;
      float su[P], st[P];
      #pragma unroll
      for (int p = 0; p < P; ++p) {
        su[p] = TU[p][(size_t)idxU[n * P + p] * 128 + e];
        st[p] = TT[p][(size_t)idxT[n * P + p] * 128 + e];
      }
      bf16* Hn = &Hs[ln * NS + e];
      #pragma unroll
      for (int k = 0; k < PP; ++k) {
        float acc = 0.f;
        #pragma unroll
        for (int i = 0; i < P; ++i) {
          int j = k + i - (P - 1);
          if (j >= 0 && j < P) acc += su[j] * st[i];
        }
        Hn[k * 136] = __float2bfloat16(acc);
      }
    }
  }
  __syncthreads();

  // ---- S = H0 @ BmatT : M=16, N=384, K=128 (8 waves x 3 col-frags) ----
  {
    bfrag a[4];
    #pragma unroll
    for (int kk = 0; kk < 4; ++kk)
      a[kk] = *(const bfrag*)&Hs[l15 * NS + kk * 32 + 8 * l4];   // row p=0
    #pragma unroll
    for (int f = 0; f < 3; ++f) {
      int col = wid * 48 + f * 16 + l15;
      ffrag acc = {0.f, 0.f, 0.f, 0.f};
      #pragma unroll
      for (int kk = 0; kk < 4; ++kk) {
        bfrag b = *(const bfrag*)&BmT[(size_t)col * 128 + kk * 32 + 8 * l4];
        acc = __builtin_amdgcn_mfma_f32_16x16x32_bf16(a[kk], b, acc, 0, 0, 0);
      }
      #pragma unroll
      for (int r = 0; r < 4; ++r) {
        int node = 4 * l4 + r;
        Ss[node * 392 + col] = __float2bfloat16(acc[r]);
      }
    }
  }
  __syncthreads();

  // ---- logits[node][h][p] = (H[p,:].S[h,:]) * 5  (1/T1) ----
  {
    int node = tid >> 5, q = tid & 31;
    if (q < NPAIR) {
      int h = q / PP, p = q - h * PP;
      const uint32_t* hrow = (const uint32_t*)&Hs[node * NS + p * 136];
      const uint32_t* srow = (const uint32_t*)&Ss[node * 392 + h * 128];
      float acc = 0.f;
      #pragma unroll 8
      for (int i = 0; i < 64; ++i) {
        uint32_t hv = hrow[i], sv = srow[i];
        acc += bflo(hv) * bflo(sv) + bfhi(hv) * bfhi(sv);
      }
      lg[node][h][p] = acc * 5.0f;
    }
  }
  __syncthreads();

  // ---- softmax over p, per (node, head) ----
  if (tid < 48) {
    int nd = tid / 3, h = tid - nd * 3;
    float mx = -1e30f;
    #pragma unroll
    for (int p = 0; p < PP; ++p) mx = fmaxf(mx, lg[nd][h][p]);
    float s = 0.f, ev[8];
    #pragma unroll
    for (int p = 0; p < PP; ++p) { ev[p] = expf(lg[nd][h][p] - mx); s += ev[p]; }
    float inv = 1.0f / s;
    #pragma unroll
    for (int p = 0; p < PP; ++p) alpha[nd][h][p] = ev[p] * inv;
  }
  __syncthreads();

  // ---- Hbar[node][h*128+e] = sum_p alpha*H  -> overwrite Ss (bf16) ----
  {
    int node = tid >> 5, q = tid & 31;
    #pragma unroll
    for (int c = 0; c < 6; ++c) {
      int o2 = q * 6 + c;             // 192 bf16-pairs per node
      int h = o2 >> 6, e = (o2 & 63) * 2;
      float a0 = 0.f, a1 = 0.f;
      #pragma unroll
      for (int p = 0; p < PP; ++p) {
        float al = alpha[node][h][p];
        uint32_t hv = *(const uint32_t*)&Hs[node * NS + p * 136 + e];
        a0 += al * bflo(hv);
        a1 += al * bfhi(hv);
      }
      Ss[node * 392 + h * 128 + e]     = __float2bfloat16(a0);
      Ss[node * 392 + h * 128 + e + 1] = __float2bfloat16(a1);
    }
  }
  __syncthreads();

  // ---- Z = Hbar @ WcT / 3 : M=16, N=128, K=384 (8 waves x 1 col-frag) ----
  {
    bfrag a[12];
    #pragma unroll
    for (int kk = 0; kk < 12; ++kk)
      a[kk] = *(const bfrag*)&Ss[l15 * 392 + kk * 32 + 8 * l4];
    int col = wid * 16 + l15;
    ffrag acc = {0.f, 0.f, 0.f, 0.f};
    #pragma unroll
    for (int kk = 0; kk < 12; ++kk) {
      bfrag b = *(const bfrag*)&WcT[(size_t)col * 384 + kk * 32 + 8 * l4];
      acc = __builtin_amdgcn_mfma_f32_16x16x32_bf16(a[kk], b, acc, 0, 0, 0);
    }
    #pragma unroll
    for (int r = 0; r < 4; ++r) {
      int gn = n0 + 4 * l4 + r;
      int crow = (((gn >> 5) * 5 + m) << 5) + (gn & 31);
      Zall[(size_t)crow * 128 + col] = acc[r] * (1.0f / 3.0f);
    }
  }
}

// ---------------- fused tail: tanh-GEMM + w + beta + pout + final MLP ------
// block = 1 batch element b, 256 threads (4 waves); grid = 512
__global__ __launch_bounds__(256) void fused_tail(
    const float* __restrict__ Zall,   // [512*160][128], row b*160+j
    const bf16* __restrict__ pw1T,    // [128][128] (o-major)
    const float* __restrict__ pb1, const float* __restrict__ pw2,
    const int* __restrict__ UI, const int* __restrict__ IU,
    const float* __restrict__ emb_user, const float* __restrict__ emb_item,
    const float* __restrict__ fw1, const float* __restrict__ fb1,
    const float* __restrict__ fw2, const float* __restrict__ fb2,
    float* __restrict__ out)
{
  __shared__ bf16 Zs[160 * 136];
  __shared__ float wrow[160];
  __shared__ float ph[2][128];
  __shared__ float xs[384];
  __shared__ float mx_s, denom_s;
  __shared__ float yred[2];

  int b = blockIdx.x, tid = threadIdx.x;
  int lane = tid & 63, wid = tid >> 6;
  int l15 = lane & 15, l4 = lane >> 4;

  // ---- stage z-block (160x128 f32) -> LDS bf16 ----
  {
    const float4* src = (const float4*)(Zall + (size_t)b * 160 * 128);
    #pragma unroll
    for (int i = 0; i < 20; ++i) {
      int v = i * 256 + tid;            // 0..5119
      int row = v >> 5, c4 = v & 31;
      float4 x = src[v];
      bf16* d = &Zs[row * 136 + c4 * 4];
      d[0] = __float2bfloat16(x.x); d[1] = __float2bfloat16(x.y);
      d[2] = __float2bfloat16(x.z); d[3] = __float2bfloat16(x.w);
    }
  }
  __syncthreads();

  // ---- w[row] = (tanh(z@pw1+pb1).pw2)*5 : M=160,N=128,K=128 ----
  for (int rf = wid; rf < 10; rf += 4) {
    bfrag a[4];
    #pragma unroll
    for (int kk = 0; kk < 4; ++kk)
      a[kk] = *(const bfrag*)&Zs[(rf * 16 + l15) * 136 + kk * 32 + 8 * l4];
    float part[4] = {0.f, 0.f, 0.f, 0.f};
    #pragma unroll
    for (int f = 0; f < 8; ++f) {
      int col = f * 16 + l15;
      ffrag acc = {0.f, 0.f, 0.f, 0.f};
      #pragma unroll
      for (int kk = 0; kk < 4; ++kk) {
        bfrag bv = *(const bfrag*)&pw1T[(size_t)col * 128 + kk * 32 + 8 * l4];
        acc = __builtin_amdgcn_mfma_f32_16x16x32_bf16(a[kk], bv, acc, 0, 0, 0);
      }
      float bias = pb1[col], w2 = pw2[col];
      #pragma unroll
      for (int r = 0; r < 4; ++r) part[r] += tanhf(acc[r] + bias) * w2;
    }
    #pragma unroll
    for (int d = 1; d < 16; d <<= 1) {
      #pragma unroll
      for (int r = 0; r < 4; ++r) part[r] += __shfl_xor(part[r], d);
    }
    if (l15 == 0) {
      #pragma unroll
      for (int r = 0; r < 4; ++r)
        wrow[rf * 16 + 4 * l4 + r] = part[r] * 5.0f;   // /T2
    }
  }
  __syncthreads();

  // ---- softmax over 160 paths ----
  if (tid == 0) {
    float mx = -1e30f;
    for (int j = 0; j < 160; ++j) mx = fmaxf(mx, wrow[j]);
    float s = 0.f;
    for (int j = 0; j < 160; ++j) s += expf(wrow[j] - mx);
    mx_s = mx; denom_s = s;
  }
  __syncthreads();
  {
    float mx = mx_s, inv = 1.0f / denom_s;
    if (tid < 160) wrow[tid] = expf(wrow[tid] - mx) * inv;
  }
  __syncthreads();

  // ---- pout[e] = sum_j beta[j]*z[j][e] ----
  {
    int e = tid & 127, half = tid >> 7;
    float acc = 0.f;
    #pragma unroll 4
    for (int j = half * 80; j < half * 80 + 80; ++j)
      acc += wrow[j] * __bfloat162float(Zs[j * 136 + e]);
    ph[half][e] = acc;
  }
  __syncthreads();

  // ---- build x = [src_emb, tgt_emb, pout] ----
  {
    int su = UI[b * 64];   // UI[b][0][0]
    int ti = IU[b * 64];   // IU[b][0][0]
    if (tid < 128) {
      xs[tid]       = emb_user[(size_t)su * 128 + tid];
      xs[256 + tid] = ph[0][tid] + ph[1][tid];
    } else {
      xs[tid]       = emb_item[(size_t)ti * 128 + (tid - 128)];
    }
  }
  __syncthreads();

  // ---- final: y = relu(x@fw1+fb1); out = sigmoid(y.fw2+fb2) ----
  {
    int o = tid & 127, half = tid >> 7;
    float acc = 0.f;
    #pragma unroll 4
    for (int i = half * 192; i < half * 192 + 192; ++i)
      acc += xs[i] * fw1[(size_t)i * 128 + o];
    __syncthreads();          // ph free now
    ph[half][o] = acc;
  }
  __syncthreads();
  if (tid < 128) {
    float y = fmaxf(ph[0][tid] + ph[1][tid] + fb1[tid], 0.0f) * fw2[tid];
    #pragma unroll
    for (int off = 32; off; off >>= 1) y += __shfl_down(y, off);
    if ((tid & 63) == 0) yred[tid >> 6] = y;
  }
  __syncthreads();
  if (tid == 0) {
    float s = yred[0] + yred[1] + fb2[0];
    out[b] = 1.0f / (1.0f + expf(-s));
  }
}

// ---------------------------------------------------------------------------
extern "C" void kernel_launch(void* const* d_in, const int* in_sizes, int n_in,
                              void* d_out, int out_size, void* d_ws, size_t ws_size,
                              hipStream_t stream)
{
  const int* UI    = (const int*)d_in[0];
  const int* IU    = (const int*)d_in[1];
  const int* UIUI  = (const int*)d_in[2];
  const int* IUIU  = (const int*)d_in[3];
  const int* UIAI1 = (const int*)d_in[4];
  const int* IAIU1 = (const int*)d_in[5];
  const int* UIAI2 = (const int*)d_in[6];
  const int* IAIU2 = (const int*)d_in[7];
  const int* UIAI3 = (const int*)d_in[8];
  const int* IAIU3 = (const int*)d_in[9];
  const float* emb_user = (const float*)d_in[10];
  const float* emb_item = (const float*)d_in[11];
  const float* emb_a1   = (const float*)d_in[12];
  const float* emb_a2   = (const float*)d_in[13];
  const float* emb_a3   = (const float*)d_in[14];
  const float* Wt  = (const float*)d_in[15];
  const float* Ws  = (const float*)d_in[16];
  const float* Wc  = (const float*)d_in[17];
  const float* pw1 = (const float*)d_in[18];
  const float* pb1 = (const float*)d_in[19];
  const float* pw2 = (const float*)d_in[20];
  const float* fw1 = (const float*)d_in[21];
  const float* fb1 = (const float*)d_in[22];
  const float* fw2 = (const float*)d_in[23];
  const float* fb2 = (const float*)d_in[24];
  float* out = (float*)d_out;

  // ---- workspace carve (bytes) ----
  char* wsb = (char*)d_ws;
  bf16*  BmT  = (bf16*)wsb;                         // 491,520 B
  bf16*  WcT  = (bf16*)(wsb + 491520);              // 491,520 B
  bf16*  pw1T = (bf16*)(wsb + 983040);              //  32,768 B
  float* Zall = (float*)(wsb + 1015808);            // 33,554,432 B

  build_BmatT<<<240, 256, 0, stream>>>(Ws, Wt, BmT);
  conv_WcT<<<960, 256, 0, stream>>>(Wc, WcT);
  conv_pw1T<<<64, 256, 0, stream>>>(pw1, pw1T);

  const float* u2[5] = {nullptr, emb_user, emb_a1, emb_a2, emb_a3};
  const float* t1[5] = {emb_user, emb_user, emb_a1, emb_a2, emb_a3};
  const int* idxU[5] = {UI, UIUI, UIAI1, UIAI2, UIAI3};
  const int* idxT[5] = {IU, IUIU, IAIU1, IAIU2, IAIU3};

  for (int m = 0; m < 5; ++m) {
    if (m == 0) {
      fused_metapath<2><<<1024, 512, 0, stream>>>(
          emb_user, emb_item, nullptr, nullptr,
          emb_item, emb_user, nullptr, nullptr,
          idxU[m], idxT[m], BmT, WcT, Zall, m);
    } else {
      fused_metapath<4><<<1024, 512, 0, stream>>>(
          emb_user, emb_item, u2[m], emb_item,
          emb_item, t1[m], emb_item, emb_user,
          idxU[m], idxT[m],
          BmT + (size_t)m * 384 * 128, WcT + (size_t)m * 128 * 384, Zall, m);
    }
  }

  fused_tail<<<512, 256, 0, stream>>>(Zall, pw1T, pb1, pw2,
                                      UI, IU, emb_user, emb_item,
                                      fw1, fb1, fw2, fb2, out);
}

// Round 4
// 216.276 us; speedup vs baseline: 3.9915x; 1.1351x over previous
//
#include <hip/hip_runtime.h>
#include <hip/hip_bf16.h>
#include <cstdint>
#include <cstddef>

// ---------------------------------------------------------------------------
// GraphHINGE, round 3: single fused metapath kernel + fast tail.
//  prep:  build_BmatT (bf16 [m][384][128]), conv_WcT (bf16 [m][128][384]),
//         conv_pw1T (bf16 [128][128])
//  fused_all (grid 5120 = 5 metapaths x 1024 tiles, 512 thr, dyn LDS 46KB):
//     gather embeddings (all loads hoisted) -> cross-correlate into LDS ->
//     S=H0@BmatT (MFMA) -> logits -> softmax -> Hbar -> Z=Hbar@WcT (MFMA)
//     -> scatter into Zall (bf16).
//  fused_tail (512 blocks x 512 thr): stage z[160][128] bf16 -> tanh-MFMA
//     -> w -> softmax(beta) -> pout -> final MLP -> sigmoid -> out[b].
// ---------------------------------------------------------------------------

typedef __hip_bfloat16 bf16;
typedef __attribute__((ext_vector_type(8))) short  bfrag;   // 8 bf16 (4 VGPR)
typedef __attribute__((ext_vector_type(4))) float  ffrag;   // 4 f32 acc

#define NNODES 16384

__device__ __forceinline__ float bflo(uint32_t u) { return __uint_as_float(u << 16); }
__device__ __forceinline__ float bfhi(uint32_t u) { return __uint_as_float(u & 0xffff0000u); }

// ---------------- prep: BmatT[m][h*128+e][ep] = Ws[m,h,e,:].Wt[m,h,ep,:] ---
__global__ __launch_bounds__(256) void build_BmatT(
    const float* __restrict__ Ws, const float* __restrict__ Wt,
    bf16* __restrict__ BmT)
{
  int mh = blockIdx.x >> 4;   // m*3+h
  int g  = blockIdx.x & 15;
  int m = mh / 3, h = mh % 3;
  const float* ws = Ws + (size_t)mh * 16384;
  const float* wt = Wt + (size_t)mh * 16384;
  int tid = threadIdx.x;
  int e = tid & 127, half = tid >> 7;
  __shared__ float wtl[2][128];
  for (int ep0 = g * 8; ep0 < g * 8 + 8; ep0 += 2) {
    int ep = ep0 + half;
    wtl[half][e] = wt[ep * 128 + e];
    __syncthreads();
    float acc = 0.f;
    #pragma unroll 4
    for (int o = 0; o < 128; ++o) acc += ws[e * 128 + o] * wtl[half][o];
    BmT[((size_t)(m * 384 + h * 128 + e)) * 128 + ep] = __float2bfloat16(acc);
    __syncthreads();
  }
}

// ---------------- prep: WcT[m][o][he] = Wc[m][he][o] -----------------------
__global__ __launch_bounds__(256) void conv_WcT(
    const float* __restrict__ Wc, bf16* __restrict__ WcT)
{
  int idx = blockIdx.x * 256 + threadIdx.x;   // < 5*128*384
  int he = idx % 384, mo = idx / 384;
  int m = mo >> 7, o = mo & 127;
  WcT[idx] = __float2bfloat16(Wc[((size_t)m * 384 + he) * 128 + o]);
}

// ---------------- prep: pw1T[o][k] = pw1[k][o] -----------------------------
__global__ __launch_bounds__(256) void conv_pw1T(
    const float* __restrict__ pw1, bf16* __restrict__ pw1T)
{
  int idx = blockIdx.x * 256 + threadIdx.x;   // < 16384
  int o = idx >> 7, k = idx & 127;
  pw1T[idx] = __float2bfloat16(pw1[(size_t)k * 128 + o]);
}

// ---------------- fused per-metapath body ----------------------------------
// block = 16 nodes, 512 threads (8 waves)
template <int P>
__device__ __forceinline__ void metapath_body(
    char* smem,
    const float* __restrict__ Tu0, const float* __restrict__ Tu1,
    const float* __restrict__ Tu2, const float* __restrict__ Tu3,
    const float* __restrict__ Tt0, const float* __restrict__ Tt1,
    const float* __restrict__ Tt2, const float* __restrict__ Tt3,
    const int* __restrict__ idxU, const int* __restrict__ idxT,
    const bf16* __restrict__ BmT,    // [384][128] (this metapath)
    const bf16* __restrict__ WcT,    // [128][384]
    bf16* __restrict__ Zall, int m, int tile)
{
  constexpr int PP = 2 * P - 1;
  constexpr int NS = PP * 136;       // node stride in Hs (bf16)
  constexpr int NPAIR = 3 * PP;
  bf16*  Hs    = (bf16*)smem;                          // 16*NS
  bf16*  Ss    = (bf16*)(smem + 16 * NS * 2);          // 16*392
  float* lg    = (float*)(smem + 16 * NS * 2 + 16 * 392 * 2);   // [16][3][8]
  float* alpha = lg + 16 * 3 * 8;

  int tid = threadIdx.x;
  int lane = tid & 63, wid = tid >> 6;
  int l15 = lane & 15, l4 = lane >> 4;
  int n0 = tile * 16;

  // ---- gather (all loads hoisted) + cross-correlate -> Hs (bf16) ----
  {
    const float* TU[4] = {Tu0, Tu1, Tu2, Tu3};
    const float* TT[4] = {Tt0, Tt1, Tt2, Tt3};
    int e = tid & 127;
    float su[4][P], st[4][P];
    #pragma unroll
    for (int g = 0; g < 4; ++g) {
      int n = n0 + g * 4 + (tid >> 7);
      #pragma unroll
      for (int p = 0; p < P; ++p) {
        su[g][p] = TU[p][(size_t)idxU[n * P + p] * 128 + e];
        st[g][p] = TT[p][(size_t)idxT[n * P + p] * 128 + e];
      }
    }
    #pragma unroll
    for (int g = 0; g < 4; ++g) {
      int ln = g * 4 + (tid >> 7);
      bf16* Hn = &Hs[ln * NS + e];
      #pragma unroll
      for (int k = 0; k < PP; ++k) {
        float acc = 0.f;
        #pragma unroll
        for (int i = 0; i < P; ++i) {
          int j = k + i - (P - 1);
          if (j >= 0 && j < P) acc += su[g][j] * st[g][i];
        }
        Hn[k * 136] = __float2bfloat16(acc);
      }
    }
  }
  __syncthreads();

  // ---- S = H0 @ BmatT : M=16, N=384, K=128 (8 waves x 3 col-frags) ----
  {
    bfrag a[4];
    #pragma unroll
    for (int kk = 0; kk < 4; ++kk)
      a[kk] = *(const bfrag*)&Hs[l15 * NS + kk * 32 + 8 * l4];   // row p=0
    #pragma unroll
    for (int f = 0; f < 3; ++f) {
      int col = wid * 48 + f * 16 + l15;
      ffrag acc = {0.f, 0.f, 0.f, 0.f};
      #pragma unroll
      for (int kk = 0; kk < 4; ++kk) {
        bfrag b = *(const bfrag*)&BmT[(size_t)col * 128 + kk * 32 + 8 * l4];
        acc = __builtin_amdgcn_mfma_f32_16x16x32_bf16(a[kk], b, acc, 0, 0, 0);
      }
      #pragma unroll
      for (int r = 0; r < 4; ++r) {
        int node = 4 * l4 + r;
        Ss[node * 392 + col] = __float2bfloat16(acc[r]);
      }
    }
  }
  __syncthreads();

  // ---- logits[node][h][p] = (H[p,:].S[h,:]) * 5  (1/T1) ----
  {
    int node = tid >> 5, q = tid & 31;
    if (q < NPAIR) {
      int h = q / PP, p = q - h * PP;
      const uint32_t* hrow = (const uint32_t*)&Hs[node * NS + p * 136];
      const uint32_t* srow = (const uint32_t*)&Ss[node * 392 + h * 128];
      float acc = 0.f;
      #pragma unroll 8
      for (int i = 0; i < 64; ++i) {
        uint32_t hv = hrow[i], sv = srow[i];
        acc += bflo(hv) * bflo(sv) + bfhi(hv) * bfhi(sv);
      }
      lg[(node * 3 + h) * 8 + p] = acc * 5.0f;
    }
  }
  __syncthreads();

  // ---- softmax over p, per (node, head) ----
  if (tid < 48) {
    float mx = -1e30f;
    #pragma unroll
    for (int p = 0; p < PP; ++p) mx = fmaxf(mx, lg[tid * 8 + p]);
    float s = 0.f, ev[8];
    #pragma unroll
    for (int p = 0; p < PP; ++p) { ev[p] = expf(lg[tid * 8 + p] - mx); s += ev[p]; }
    float inv = 1.0f / s;
    #pragma unroll
    for (int p = 0; p < PP; ++p) alpha[tid * 8 + p] = ev[p] * inv;
  }
  __syncthreads();

  // ---- Hbar[node][h*128+e] = sum_p alpha*H  -> overwrite Ss (bf16) ----
  {
    int node = tid >> 5, q = tid & 31;
    #pragma unroll
    for (int c = 0; c < 6; ++c) {
      int o2 = q * 6 + c;             // 192 bf16-pairs per node
      int h = o2 >> 6, e = (o2 & 63) * 2;
      float a0 = 0.f, a1 = 0.f;
      #pragma unroll
      for (int p = 0; p < PP; ++p) {
        float al = alpha[(node * 3 + h) * 8 + p];
        uint32_t hv = *(const uint32_t*)&Hs[node * NS + p * 136 + e];
        a0 += al * bflo(hv);
        a1 += al * bfhi(hv);
      }
      Ss[node * 392 + h * 128 + e]     = __float2bfloat16(a0);
      Ss[node * 392 + h * 128 + e + 1] = __float2bfloat16(a1);
    }
  }
  __syncthreads();

  // ---- Z = Hbar @ WcT / 3 : M=16, N=128, K=384 (8 waves x 1 col-frag) ----
  {
    bfrag a[12];
    #pragma unroll
    for (int kk = 0; kk < 12; ++kk)
      a[kk] = *(const bfrag*)&Ss[l15 * 392 + kk * 32 + 8 * l4];
    int col = wid * 16 + l15;
    ffrag acc = {0.f, 0.f, 0.f, 0.f};
    #pragma unroll
    for (int kk = 0; kk < 12; ++kk) {
      bfrag b = *(const bfrag*)&WcT[(size_t)col * 384 + kk * 32 + 8 * l4];
      acc = __builtin_amdgcn_mfma_f32_16x16x32_bf16(a[kk], b, acc, 0, 0, 0);
    }
    #pragma unroll
    for (int r = 0; r < 4; ++r) {
      int gn = n0 + 4 * l4 + r;
      int crow = (((gn >> 5) * 5 + m) << 5) + (gn & 31);
      Zall[(size_t)crow * 128 + col] = __float2bfloat16(acc[r] * (1.0f / 3.0f));
    }
  }
}

// ---------------- all 5 metapaths in one launch ----------------------------
// grid = 5120: bid>>10 = m, bid&1023 = tile
__global__ __launch_bounds__(512) void fused_all(
    const float* __restrict__ emb_user, const float* __restrict__ emb_item,
    const float* __restrict__ emb_a1, const float* __restrict__ emb_a2,
    const float* __restrict__ emb_a3,
    const int* __restrict__ UI,    const int* __restrict__ IU,
    const int* __restrict__ UIUI,  const int* __restrict__ IUIU,
    const int* __restrict__ UIAI1, const int* __restrict__ IAIU1,
    const int* __restrict__ UIAI2, const int* __restrict__ IAIU2,
    const int* __restrict__ UIAI3, const int* __restrict__ IAIU3,
    const bf16* __restrict__ BmT, const bf16* __restrict__ WcT,
    bf16* __restrict__ Zall)
{
  extern __shared__ char smem[];
  int bid = blockIdx.x;
  int m = bid >> 10, tile = bid & 1023;
  if (m == 0) {
    metapath_body<2>(smem, emb_user, emb_item, nullptr, nullptr,
                     emb_item, emb_user, nullptr, nullptr,
                     UI, IU, BmT, WcT, Zall, 0, tile);
  } else {
    const float* u2 = (m == 1) ? emb_user : (m == 2) ? emb_a1
                    : (m == 3) ? emb_a2 : emb_a3;
    const int* iu_ = (m == 1) ? UIUI : (m == 2) ? UIAI1
                   : (m == 3) ? UIAI2 : UIAI3;
    const int* it_ = (m == 1) ? IUIU : (m == 2) ? IAIU1
                   : (m == 3) ? IAIU2 : IAIU3;
    metapath_body<4>(smem, emb_user, emb_item, u2, emb_item,
                     emb_item, u2, emb_item, emb_user,
                     iu_, it_,
                     BmT + (size_t)m * 49152, WcT + (size_t)m * 49152,
                     Zall, m, tile);
  }
}

// ---------------- fused tail: tanh-GEMM + w + beta + pout + final MLP ------
// block = 1 batch element b, 512 threads (8 waves); grid = 512
__global__ __launch_bounds__(512) void fused_tail(
    const bf16* __restrict__ Zall,    // [512*160][128], row b*160+j
    const bf16* __restrict__ pw1T,    // [128][128] (o-major)
    const float* __restrict__ pb1, const float* __restrict__ pw2,
    const int* __restrict__ UI, const int* __restrict__ IU,
    const float* __restrict__ emb_user, const float* __restrict__ emb_item,
    const float* __restrict__ fw1, const float* __restrict__ fb1,
    const float* __restrict__ fw2, const float* __restrict__ fb2,
    float* __restrict__ out)
{
  __shared__ bf16 Zs[160 * 136];
  __shared__ float wrow[160];
  __shared__ float ph[4][128];
  __shared__ float xs[384];
  __shared__ float sred[16];
  __shared__ float yred[2];

  int b = blockIdx.x, tid = threadIdx.x;
  int lane = tid & 63, wid = tid >> 6;
  int l15 = lane & 15, l4 = lane >> 4;

  // ---- stage z-block (160x128 bf16) -> LDS, raw 16B copies, hoisted ----
  {
    const float4* src = (const float4*)(Zall + (size_t)b * 160 * 128);
    float4 v[5];
    #pragma unroll
    for (int i = 0; i < 5; ++i) v[i] = src[i * 512 + tid];
    #pragma unroll
    for (int i = 0; i < 5; ++i) {
      int idx = i * 512 + tid;            // 0..2559
      int row = idx >> 4, c8 = idx & 15;
      *(float4*)&Zs[row * 136 + c8 * 8] = v[i];
    }
  }
  __syncthreads();

  // ---- w[row] = (tanh(z@pw1+pb1).pw2)*5 : M=160,N=128,K=128 ----
  for (int rf = wid; rf < 10; rf += 8) {
    bfrag a[4];
    #pragma unroll
    for (int kk = 0; kk < 4; ++kk)
      a[kk] = *(const bfrag*)&Zs[(rf * 16 + l15) * 136 + kk * 32 + 8 * l4];
    float part[4] = {0.f, 0.f, 0.f, 0.f};
    #pragma unroll
    for (int f = 0; f < 8; ++f) {
      int col = f * 16 + l15;
      ffrag acc = {0.f, 0.f, 0.f, 0.f};
      #pragma unroll
      for (int kk = 0; kk < 4; ++kk) {
        bfrag bv = *(const bfrag*)&pw1T[(size_t)col * 128 + kk * 32 + 8 * l4];
        acc = __builtin_amdgcn_mfma_f32_16x16x32_bf16(a[kk], bv, acc, 0, 0, 0);
      }
      float bias = pb1[col], w2 = pw2[col];
      #pragma unroll
      for (int r = 0; r < 4; ++r) part[r] += tanhf(acc[r] + bias) * w2;
    }
    #pragma unroll
    for (int d = 1; d < 16; d <<= 1) {
      #pragma unroll
      for (int r = 0; r < 4; ++r) part[r] += __shfl_xor(part[r], d);
    }
    if (l15 == 0) {
      #pragma unroll
      for (int r = 0; r < 4; ++r)
        wrow[rf * 16 + 4 * l4 + r] = part[r] * 5.0f;   // /T2
    }
  }
  __syncthreads();

  // ---- softmax over 160 paths (wave-parallel) ----
  {
    float v = (tid < 160) ? wrow[tid] : -1e30f;
    #pragma unroll
    for (int off = 32; off; off >>= 1) v = fmaxf(v, __shfl_xor(v, off));
    if (lane == 0) sred[wid] = v;
    __syncthreads();
    if (tid < 64) {
      float mval = (lane < 8) ? sred[lane] : -1e30f;
      #pragma unroll
      for (int off = 4; off; off >>= 1) mval = fmaxf(mval, __shfl_xor(mval, off));
      if (lane == 0) sred[8] = mval;
    }
    __syncthreads();
    float mx = sred[8];
    float ev = (tid < 160) ? expf(wrow[tid] - mx) : 0.f;
    float s = ev;
    #pragma unroll
    for (int off = 32; off; off >>= 1) s += __shfl_xor(s, off);
    if (lane == 0) sred[wid] = s;
    __syncthreads();
    if (tid < 64) {
      float sval = (lane < 8) ? sred[lane] : 0.f;
      #pragma unroll
      for (int off = 4; off; off >>= 1) sval += __shfl_xor(sval, off);
      if (lane == 0) sred[9] = sval;
    }
    __syncthreads();
    if (tid < 160) wrow[tid] = ev / sred[9];
  }
  __syncthreads();

  // ---- pout[e] = sum_j beta[j]*z[j][e]  (4-way split over j) ----
  {
    int e = tid & 127, q = tid >> 7;
    float acc = 0.f;
    #pragma unroll 4
    for (int j = q * 40; j < q * 40 + 40; ++j)
      acc += wrow[j] * __bfloat162float(Zs[j * 136 + e]);
    ph[q][e] = acc;
  }
  __syncthreads();

  // ---- build x = [src_emb, tgt_emb, pout] ----
  {
    int su = UI[b * 64];   // UI[b][0][0]
    int ti = IU[b * 64];   // IU[b][0][0]
    if (tid < 128) {
      xs[256 + tid] = ph[0][tid] + ph[1][tid] + ph[2][tid] + ph[3][tid];
    } else if (tid < 256) {
      xs[tid - 128] = emb_user[(size_t)su * 128 + (tid - 128)];
    } else if (tid < 384) {
      xs[tid - 128] = emb_item[(size_t)ti * 128 + (tid - 256)];
    }
  }
  __syncthreads();

  // ---- final: y = relu(x@fw1+fb1); out = sigmoid(y.fw2+fb2) ----
  {
    int o = tid & 127, q = tid >> 7;
    float acc = 0.f;
    #pragma unroll 4
    for (int i = q * 96; i < q * 96 + 96; ++i)
      acc += xs[i] * fw1[(size_t)i * 128 + o];
    __syncthreads();          // ph free now
    ph[q][o] = acc;
  }
  __syncthreads();
  if (tid < 128) {
    float y = fmaxf(ph[0][tid] + ph[1][tid] + ph[2][tid] + ph[3][tid] + fb1[tid],
                    0.0f) * fw2[tid];
    #pragma unroll
    for (int off = 32; off; off >>= 1) y += __shfl_down(y, off);
    if ((tid & 63) == 0) yred[tid >> 6] = y;
  }
  __syncthreads();
  if (tid == 0) {
    float s = yred[0] + yred[1] + fb2[0];
    out[b] = 1.0f / (1.0f + expf(-s));
  }
}

// ---------------------------------------------------------------------------
extern "C" void kernel_launch(void* const* d_in, const int* in_sizes, int n_in,
                              void* d_out, int out_size, void* d_ws, size_t ws_size,
                              hipStream_t stream)
{
  const int* UI    = (const int*)d_in[0];
  const int* IU    = (const int*)d_in[1];
  const int* UIUI  = (const int*)d_in[2];
  const int* IUIU  = (const int*)d_in[3];
  const int* UIAI1 = (const int*)d_in[4];
  const int* IAIU1 = (const int*)d_in[5];
  const int* UIAI2 = (const int*)d_in[6];
  const int* IAIU2 = (const int*)d_in[7];
  const int* UIAI3 = (const int*)d_in[8];
  const int* IAIU3 = (const int*)d_in[9];
  const float* emb_user = (const float*)d_in[10];
  const float* emb_item = (const float*)d_in[11];
  const float* emb_a1   = (const float*)d_in[12];
  const float* emb_a2   = (const float*)d_in[13];
  const float* emb_a3   = (const float*)d_in[14];
  const float* Wt  = (const float*)d_in[15];
  const float* Ws  = (const float*)d_in[16];
  const float* Wc  = (const float*)d_in[17];
  const float* pw1 = (const float*)d_in[18];
  const float* pb1 = (const float*)d_in[19];
  const float* pw2 = (const float*)d_in[20];
  const float* fw1 = (const float*)d_in[21];
  const float* fb1 = (const float*)d_in[22];
  const float* fw2 = (const float*)d_in[23];
  const float* fb2 = (const float*)d_in[24];
  float* out = (float*)d_out;

  // ---- workspace carve (bytes) ----
  char* wsb = (char*)d_ws;
  bf16*  BmT  = (bf16*)wsb;                         // 491,520 B
  bf16*  WcT  = (bf16*)(wsb + 491520);              // 491,520 B
  bf16*  pw1T = (bf16*)(wsb + 983040);              //  32,768 B
  bf16*  Zall = (bf16*)(wsb + 1015808);             // 20,971,520 B

  build_BmatT<<<240, 256, 0, stream>>>(Ws, Wt, BmT);
  conv_WcT<<<960, 256, 0, stream>>>(Wc, WcT);
  conv_pw1T<<<64, 256, 0, stream>>>(pw1, pw1T);

  // dyn LDS: Hs 16*952*2 + Ss 16*392*2 + lg/alpha 2*1536 = 46080 B
  fused_all<<<5120, 512, 46080, stream>>>(
      emb_user, emb_item, emb_a1, emb_a2, emb_a3,
      UI, IU, UIUI, IUIU, UIAI1, IAIU1, UIAI2, IAIU2, UIAI3, IAIU3,
      BmT, WcT, Zall);

  fused_tail<<<512, 512, 0, stream>>>(Zall, pw1T, pb1, pw2,
                                      UI, IU, emb_user, emb_item,
                                      fw1, fb1, fw2, fb2, out);
}